// Round 12
// baseline (199.827 us; speedup 1.0000x reference)
//
#include <hip/hip_runtime.h>
#include <hip/hip_bf16.h>

typedef short bf16x8 __attribute__((ext_vector_type(8)));
typedef short bf16x4 __attribute__((ext_vector_type(4)));
typedef float f32x4 __attribute__((ext_vector_type(4)));

#define ALPHA_Q 0.1803368801111204f   // 0.125 * log2(e): softmax scale + exp2 base folded into q

static __device__ __forceinline__ unsigned short f2bf(float f) {
  unsigned u = __float_as_uint(f);
  u += 0x7fffu + ((u >> 16) & 1u);           // RNE
  return (unsigned short)(u >> 16);
}
static __device__ __forceinline__ float bf2f(unsigned short h) {
  return __uint_as_float((unsigned)h << 16);
}

// ---------------------------------------------------------------------------
// One prep kernel: 4x weight fp32->bf16 convert + pe table builds.
// ---------------------------------------------------------------------------
struct PrepArgs {
  const float* W[4];
  unsigned short* Wb[4];
  const float* pe;
  unsigned short *pe_b, *peT1, *peB, *peBb;
};

__global__ __launch_bounds__(256) void prep_all(PrepArgs pa) {
  const int bid = blockIdx.x;
  const int t = threadIdx.x;
  if (bid < 1024) {
    const int w = bid >> 8;
    const int i = ((bid & 255) << 8) + t;      // < 65536 float4s
    float4 v = ((const float4*)pa.W[w])[i];
    uint2 o;
    o.x = (unsigned)f2bf(v.x) | ((unsigned)f2bf(v.y) << 16);
    o.y = (unsigned)f2bf(v.z) | ((unsigned)f2bf(v.w) << 16);
    ((uint2*)pa.Wb[w])[i] = o;
  } else {
    const int i = ((bid - 1024) << 8) + t;     // < 40960
    const float* pe = pa.pe;
    if (i < 608 * 64) {
      int r = i >> 6, d = i & 63;
      pa.pe_b[i] = (r <= 512) ? f2bf(pe[r * 64 + d]) : (unsigned short)0;
    }
    if (i < 64 * 640) {
      int d = i / 640, y = i % 640;
      pa.peT1[i] = (y < 512) ? f2bf(pe[(y + 1) * 64 + d]) : (unsigned short)0;
    }
    if (i < 64 * 128) {
      int d = i >> 7, u = i & 127;
      pa.peB[i] = f2bf(pe[(u > 63 ? u - 63 : 0) * 64 + d]);
    }
    if (i < 128 * 64) {
      int v = i >> 6, d = i & 63;
      pa.peBb[i] = f2bf(pe[(v > 63 ? v - 63 : 0) * 64 + d]);
    }
  }
}

// ---------------------------------------------------------------------------
// NT GEMM via MFMA: Y[m][n] = (sum_k A[m][k]*W[n][k] + bias[n]) * scale
// ---------------------------------------------------------------------------
struct GemmArgs {
  const void* X[3];
  const unsigned short* W[3];
  const float* bias[3];
  float scale[3];
  unsigned short* Yb[3];
  float* Yf;
};

template<int AFP32>
__global__ __launch_bounds__(512) void gemm_nt(GemmArgs ga) {
  __shared__ __align__(16) unsigned short asb[2][128][72];
  __shared__ __align__(16) unsigned short bsb[2][64][72];
  const int z = blockIdx.z;
  const void* Xv = ga.X[z];
  const unsigned short* W = ga.W[z];
  const int t = threadIdx.x;
  const int wid = t >> 6, lane = t & 63;
  const int l15 = lane & 15, l4 = lane >> 4;
  const int n0 = blockIdx.x << 6, m0 = blockIdx.y << 7;
  const int wr0 = wid << 4;

  f32x4 acc[4];
#pragma unroll
  for (int j = 0; j < 4; ++j) acc[j] = (f32x4){0.f, 0.f, 0.f, 0.f};

  auto stage = [&](int k0, int buf) {
    if (AFP32) {
      const float* X = (const float*)Xv;
#pragma unroll
      for (int i = 0; i < 4; ++i) {
        int idx = t + (i << 9);
        int row = idx >> 4, c4 = (idx & 15) << 2;
        float4 v = *(const float4*)(X + (size_t)(m0 + row) * 512 + k0 + c4);
        uint2 o;
        o.x = (unsigned)f2bf(v.x) | ((unsigned)f2bf(v.y) << 16);
        o.y = (unsigned)f2bf(v.z) | ((unsigned)f2bf(v.w) << 16);
        *(uint2*)&asb[buf][row][c4] = o;
      }
    } else {
      const unsigned short* X = (const unsigned short*)Xv;
#pragma unroll
      for (int i = 0; i < 2; ++i) {
        int idx = t + (i << 9);
        int row = idx >> 3, g8 = (idx & 7) << 3;
        *(bf16x8*)&asb[buf][row][g8] = *(const bf16x8*)(X + (size_t)(m0 + row) * 512 + k0 + g8);
      }
    }
    int row = t >> 3, g8 = (t & 7) << 3;
    *(bf16x8*)&bsb[buf][row][g8] = *(const bf16x8*)(W + (size_t)(n0 + row) * 512 + k0 + g8);
  };

  stage(0, 0);
  __syncthreads();
  for (int it = 0; it < 8; ++it) {
    const int buf = it & 1;
    if (it < 7) stage((it + 1) << 6, buf ^ 1);
#pragma unroll
    for (int ks = 0; ks < 2; ++ks) {
      bf16x8 af = *(const bf16x8*)&asb[buf][wr0 + l15][(ks << 5) + (l4 << 3)];
#pragma unroll
      for (int j = 0; j < 4; ++j) {
        bf16x8 bw = *(const bf16x8*)&bsb[buf][(j << 4) + l15][(ks << 5) + (l4 << 3)];
        acc[j] = __builtin_amdgcn_mfma_f32_16x16x32_bf16(af, bw, acc[j], 0, 0, 0);
      }
    }
    __syncthreads();
  }

  const float* bias = ga.bias[z];
  const float scale = ga.scale[z];
#pragma unroll
  for (int j = 0; j < 4; ++j) {
    const int n = n0 + (j << 4) + l15;
    const float bn = bias[n];
#pragma unroll
    for (int r = 0; r < 4; ++r) {
      const int m = m0 + wr0 + (l4 << 2) + r;
      float v = (acc[j][r] + bn) * scale;
      if (AFP32) ga.Yb[z][(size_t)m * 512 + n] = f2bf(v);
      else       ga.Yf[(size_t)m * 512 + n] = v;
    }
  }
}

// ---------------------------------------------------------------------------
// Fused causal attention + relative terms. SWAPPED-QK (round-9 frame):
// Block = (b,h, 64 q-rows), 4 waves, 256 thr, 36.4 KB LDS, 1024 blocks.
// CU-balanced tile table: tile(w=bid>>8, a=(bid>>6)&3) with per-CU sums
// equal (34 chunk-works each); 4 blocks/CU co-resident (launch_bounds 256,4).
// ---------------------------------------------------------------------------
__global__ __launch_bounds__(256, 4) void attn_mfma(
    const unsigned short* __restrict__ qb,
    const unsigned short* __restrict__ kb,
    const unsigned short* __restrict__ vb,
    const unsigned short* __restrict__ pe_b,
    const unsigned short* __restrict__ peT1,
    const unsigned short* __restrict__ peB,
    const unsigned short* __restrict__ peBb,
    const float* __restrict__ pe,
    unsigned short* __restrict__ Oa) {
  const int bid = blockIdx.x;
  const int bh  = ((bid & 7) << 3) | ((bid >> 3) & 7);  // XCD-grouped (b = XCD)
  const int b = bh >> 3, h = bh & 7;
  // Balanced tile table: each CU's 4 resident blocks (bid, +256, +512, +768)
  // get tiles {15-a, 8+a, 4+a, 3-a} -> sum 30 for every a (uniform 34 chunks).
  const int w2 = bid >> 8, a2 = (bid >> 6) & 3;
  const int tile = (w2 == 0) ? (15 - a2) : (w2 == 1) ? (8 + a2)
                 : (w2 == 2) ? (4 + a2)  : (3 - a2);
  const int l0 = tile << 6;
  const int nch = tile + 1;

  const int t = threadIdx.x;
  const int wid = t >> 6, lane = t & 63;
  const int l15 = lane & 15, l4 = lane >> 4;
  const int wr0 = wid << 4;
  const int rowb = wr0 + (l4 << 2);
  const int qrow = wr0 + l15;            // swapped: this lane's q row
  const int lq = l0 + qrow;

  __shared__ __align__(16) char smem[36352];
  unsigned short (*ksb)[72]   = (unsigned short(*)[72])(smem);            //  9216 B
  unsigned short (*vtb)[72]   = (unsigned short(*)[72])(smem + 9216);     //  9216 B
  unsigned short (*band)[136] = (unsigned short(*)[136])(smem + 18432);   // 17408 B
  float* den_lds              = (float*)(smem + 35840);                   //   256 B
  float* pr0_lds              = (float*)(smem + 36096);                   //   256 B

  // zero band once; masked writes keep each row's complement zero forever
  {
    unsigned int* zp = (unsigned int*)&band[0][0];
#pragma unroll
    for (int i = 0; i < 17; ++i) zp[t + (i << 8)] = 0u;
  }

  // q fragments (pre-scaled by ALPHA_Q in projection)
  bf16x8 aq[2];
  {
    const unsigned short* qp_ = qb + (size_t)(b * 1024 + l0 + qrow) * 512 + h * 64 + (l4 << 3);
    aq[0] = *(const bf16x8*)qp_;
    aq[1] = *(const bf16x8*)(qp_ + 32);
  }

  // qa0 = q . pe[0] for this lane's qrow (register resident in swapped layout)
  float qa0;
  {
    float part = 0.f;
#pragma unroll
    for (int ks = 0; ks < 2; ++ks)
#pragma unroll
      for (int i = 0; i < 8; ++i)
        part += bf2f((unsigned short)aq[ks][i]) * pe[(ks << 5) + (l4 << 3) + i];
    part += __shfl_xor(part, 16, 64);
    part += __shfl_xor(part, 32, 64);
    qa0 = part;
  }

  f32x4 ov[4], ow[4];
#pragma unroll
  for (int f = 0; f < 4; ++f) {
    ov[f] = (f32x4){0.f, 0.f, 0.f, 0.f};
    ow[f] = (f32x4){0.f, 0.f, 0.f, 0.f};
  }
  float denT = 0.f, pr0T = 0.f;

  const int srow0 = t >> 3, sg = t & 7;
  bf16x8 kreg[2], vreg[2];
  auto LOADKV = [&](int cc) {
#pragma unroll
    for (int i = 0; i < 2; ++i) {
      const size_t ga = (size_t)(b * 1024 + (cc << 6) + srow0 + (i << 5)) * 512 + h * 64 + (sg << 3);
      kreg[i] = *(const bf16x8*)(kb + ga);
      vreg[i] = *(const bf16x8*)(vb + ga);
    }
  };
  auto WRITEKV = [&]() {
#pragma unroll
    for (int i = 0; i < 2; ++i) {
      const int row = srow0 + (i << 5);
      *(bf16x8*)&ksb[row][sg << 3] = kreg[i];
      const int col = (((row >> 3) ^ sg) << 3) + (row & 7);  // bank-uniform transpose
#pragma unroll
      for (int j = 0; j < 8; ++j)
        vtb[(sg << 3) + j][col] = (unsigned short)vreg[i][j];
    }
  };

  LOADKV(0);
  WRITEKV();
  __syncthreads();

  const int f8lo = 3 - wid;              // bias v-window per wave: [48-16w, 127-16w]
  const int k2lo = (wid < 2) ? 1 : 0;    // out-band: wave's zero k-slice skipped
  // bpermute source lanes for PV A-frag build (byte indices)
  const int src0 = (l15 + ((((l4 << 1) + 0) & 3) << 4)) << 2;
  const int src1 = (l15 + ((((l4 << 1) + 1) & 3) << 4)) << 2;
  const bool hi4 = (l4 >= 2);

  for (int c = 0; c < nch; ++c) {
    const int s0 = c << 6;
    const bool clipped = (c <= tile - 9);   // all s-l <= -512 -> pe row 0
    const bool bnd = (c == tile - 8);       // band straddles the clip point
    if (c + 1 < nch) LOADKV(c + 1);         // T14: issue early, write after barrier

    // ---- QK^T (swapped): sc[f][r] = S[s=s0+16f+4*l4+r][q=qrow] ----
    f32x4 sc[4];
#pragma unroll
    for (int f = 0; f < 4; ++f) sc[f] = (f32x4){0.f, 0.f, 0.f, 0.f};
    __builtin_amdgcn_s_setprio(1);
#pragma unroll
    for (int ks = 0; ks < 2; ++ks)
#pragma unroll
      for (int f = 0; f < 4; ++f) {
        bf16x8 bk = *(const bf16x8*)&ksb[(f << 4) + l15][(ks << 5) + (l4 << 3)];
        sc[f] = __builtin_amdgcn_mfma_f32_16x16x32_bf16(bk, aq[ks], sc[f], 0, 0, 0);
      }
    __builtin_amdgcn_s_setprio(0);

    // ---- transposed bias GEMM: D[v][qrow] = pe[v+voff].q, B-frags INLINE ----
    if (!clipped) {
      const unsigned short* bsrcB = bnd ? peBb : (pe_b + (size_t)(s0 - l0 + 449) * 64);
      f32x4 macc[5];
#pragma unroll
      for (int i = 0; i < 5; ++i) macc[i] = (f32x4){0.f, 0.f, 0.f, 0.f};
      __builtin_amdgcn_s_setprio(1);
#pragma unroll
      for (int i = 0; i < 5; ++i) {
        const unsigned short* p_ = bsrcB + (size_t)(((f8lo + i) << 4) + l15) * 64 + (l4 << 3);
        bf16x8 bp0 = *(const bf16x8*)p_;
        bf16x8 bp1 = *(const bf16x8*)(p_ + 32);
        macc[i] = __builtin_amdgcn_mfma_f32_16x16x32_bf16(bp0, aq[0], macc[i], 0, 0, 0);
        macc[i] = __builtin_amdgcn_mfma_f32_16x16x32_bf16(bp1, aq[1], macc[i], 0, 0, 0);
      }
      __builtin_amdgcn_s_setprio(0);
      const int Aw = 63 - qrow, Bw = 126 - qrow;   // row's valid u window
#pragma unroll
      for (int i = 0; i < 5; ++i) {
        const int v0 = ((f8lo + i) << 4) + (l4 << 2);
        if (v0 >= Aw && v0 + 3 <= Bw) {
          bf16x4 pk;
#pragma unroll
          for (int r = 0; r < 4; ++r) pk[r] = (short)f2bf(macc[i][r]);
          *(bf16x4*)&band[qrow][v0] = pk;
        } else if (v0 + 3 >= Aw && v0 <= Bw) {
#pragma unroll
          for (int r = 0; r < 4; ++r) {
            const int v = v0 + r;
            if (v >= Aw && v <= Bw) band[qrow][v] = f2bf(macc[i][r]);
          }
        }
      }
    }

    // ---- P-phase (swapped): bias from band at (qrow,u), exp2, pack P ----
    unsigned int dw[4][2];
#pragma unroll
    for (int f = 0; f < 4; ++f) {
#pragma unroll
      for (int h2 = 0; h2 < 2; ++h2) {
        unsigned int dword = 0;
#pragma unroll
        for (int rr = 0; rr < 2; ++rr) {
          const int r = (h2 << 1) + rr;
          const int slocal = (f << 4) + (l4 << 2) + r;
          const int s = s0 + slocal;
          const int u = slocal + 63 - qrow;
          const float qa = clipped ? qa0 : bf2f(band[qrow][u]);
          float p = exp2f(sc[f][r] + qa);
          p = (s <= lq) ? p : 0.f;
          denT += p;
          const unsigned short pbf = f2bf(p);
          if (!clipped) band[qrow][u] = pbf;
          else pr0T += p;
          dword |= ((unsigned)pbf) << (rr << 4);
        }
        dw[f][h2] = dword;
      }
    }

    // ---- PV: build A-frags in-register (bpermute across l4 group) ----
    __builtin_amdgcn_s_setprio(1);
#pragma unroll
    for (int ks = 0; ks < 2; ++ks) {
      const int flo = ks << 1, fhi = flo + 1;
      int a0lo = __builtin_amdgcn_ds_bpermute(src0, (int)dw[flo][0]);
      int a0hi = __builtin_amdgcn_ds_bpermute(src0, (int)dw[fhi][0]);
      int a1lo = __builtin_amdgcn_ds_bpermute(src0, (int)dw[flo][1]);
      int a1hi = __builtin_amdgcn_ds_bpermute(src0, (int)dw[fhi][1]);
      int a2lo = __builtin_amdgcn_ds_bpermute(src1, (int)dw[flo][0]);
      int a2hi = __builtin_amdgcn_ds_bpermute(src1, (int)dw[fhi][0]);
      int a3lo = __builtin_amdgcn_ds_bpermute(src1, (int)dw[flo][1]);
      int a3hi = __builtin_amdgcn_ds_bpermute(src1, (int)dw[fhi][1]);
      union { int i4[4]; bf16x8 v8; } au;
      au.i4[0] = hi4 ? a0hi : a0lo;
      au.i4[1] = hi4 ? a1hi : a1lo;
      au.i4[2] = hi4 ? a2hi : a2lo;
      au.i4[3] = hi4 ? a3hi : a3lo;
#pragma unroll
      for (int f = 0; f < 4; ++f) {
        const int d = (f << 4) + l15;
        const int U = ((ks << 2) + l4) ^ ((d >> 3) & 7);
        bf16x8 bv = *(const bf16x8*)&vtb[d][U << 3];
        ov[f] = __builtin_amdgcn_mfma_f32_16x16x32_bf16(au.v8, bv, ov[f], 0, 0, 0);
      }
    }
    __builtin_amdgcn_s_setprio(0);

    __syncthreads();                 // all waves done with ksb/vtb
    if (c + 1 < nch) WRITEKV();

    // ---- out-band GEMM: ow += peW . band (3 k-slices, A-frags INLINE) ----
    if (!clipped) {
      const unsigned short* asrc = bnd ? peB : (peT1 + (s0 - l0 + 448));
      const int astr = bnd ? 128 : 640;
      bf16x8 bb[3];
#pragma unroll
      for (int k = 0; k < 3; ++k)
        bb[k] = *(const bf16x8*)&band[wr0 + l15][((k2lo + k) << 5) + (l4 << 3)];
      __builtin_amdgcn_s_setprio(1);
#pragma unroll
      for (int fd = 0; fd < 4; ++fd)
#pragma unroll
        for (int k = 0; k < 3; ++k) {
          bf16x8 af = *(const bf16x8*)(asrc + (size_t)((fd << 4) + l15) * astr + ((k2lo + k) << 5) + (l4 << 3));
          ow[fd] = __builtin_amdgcn_mfma_f32_16x16x32_bf16(af, bb[k], ow[fd], 0, 0, 0);
        }
      __builtin_amdgcn_s_setprio(0);
    }
    __syncthreads();                 // staged K/V visible; band free next chunk
  }

  // ---- publish den/pr0 per q-row (reduce over l4 group; wave-private LDS) ----
  denT += __shfl_xor(denT, 16, 64);
  denT += __shfl_xor(denT, 32, 64);
  pr0T += __shfl_xor(pr0T, 16, 64);
  pr0T += __shfl_xor(pr0T, 32, 64);
  if (l4 == 0) {
    den_lds[qrow] = denT;
    pr0_lds[qrow] = pr0T;
  }
  float den_j[4], pr0_j[4];
#pragma unroll
  for (int j = 0; j < 4; ++j) {
    den_j[j] = den_lds[rowb + j];
    pr0_j[j] = pr0_lds[rowb + j];
  }

  // clipped-region contribution: pr0 * pe[0][d]
#pragma unroll
  for (int f = 0; f < 4; ++f) {
    const float pe0 = pe[(f << 4) + l15];
#pragma unroll
    for (int j = 0; j < 4; ++j) ov[f][j] += pr0_j[j] * pe0;
  }

  // ---- transpose ow in the wave's PRIVATE band rows (wave-synchronous) ----
  float (*tbw)[17] = (float(*)[17])&band[wr0][0];   // 16 rows * 272 B = [64][17] f32
#pragma unroll
  for (int fd = 0; fd < 4; ++fd)
#pragma unroll
    for (int r = 0; r < 4; ++r)
      tbw[(fd << 4) + (l4 << 2) + r][l15] = ow[fd][r];

  // ---- normalize + store bf16 ----
#pragma unroll
  for (int j = 0; j < 4; ++j) {
    const float inv = 1.f / den_j[j];
    unsigned short* dst = Oa + (size_t)(b * 1024 + l0 + rowb + j) * 512 + h * 64;
#pragma unroll
    for (int f = 0; f < 4; ++f) {
      const float o2 = tbw[(f << 4) + l15][(l4 << 2) + j];
      dst[(f << 4) + l15] = f2bf((ov[f][j] + o2) * inv);
    }
  }
}

// ---------------------------------------------------------------------------
extern "C" void kernel_launch(void* const* d_in, const int* in_sizes, int n_in,
                              void* d_out, int out_size, void* d_ws, size_t ws_size,
                              hipStream_t stream) {
  const float* query = (const float*)d_in[0];
  const float* key   = (const float*)d_in[1];
  const float* value = (const float*)d_in[2];
  // d_in[3] attention_mask == 1 -> causal
  const float* Wq = (const float*)d_in[4];
  const float* bq = (const float*)d_in[5];
  const float* Wk = (const float*)d_in[6];
  const float* bk = (const float*)d_in[7];
  const float* Wv = (const float*)d_in[8];
  const float* bv = (const float*)d_in[9];
  const float* pe = (const float*)d_in[10];
  const float* Wo = (const float*)d_in[11];
  const float* bo = (const float*)d_in[12];

  char* ws = (char*)d_ws;
  const size_t SZ_QKV = (size_t)8192 * 512 * 2;           // 8,388,608
  unsigned short* qbuf = (unsigned short*)(ws);
  unsigned short* kbuf = (unsigned short*)(ws + SZ_QKV);
  unsigned short* vbuf = (unsigned short*)(ws + 2 * SZ_QKV);
  unsigned short* obuf = (unsigned short*)(ws + 3 * SZ_QKV);
  char* wbase = ws + 4 * SZ_QKV;
  unsigned short* Wqb  = (unsigned short*)(wbase);
  unsigned short* Wkb  = (unsigned short*)(wbase + 524288);
  unsigned short* Wvb  = (unsigned short*)(wbase + 2 * 524288);
  unsigned short* Wob  = (unsigned short*)(wbase + 3 * 524288);
  unsigned short* pe_b = (unsigned short*)(wbase + 4 * 524288);
  unsigned short* peT1 = (unsigned short*)(wbase + 4 * 524288 + 77824);
  unsigned short* peB  = (unsigned short*)(wbase + 4 * 524288 + 77824 + 81920);
  unsigned short* peBb = (unsigned short*)(wbase + 4 * 524288 + 77824 + 81920 + 16384);
  if (ws_size < (size_t)4 * SZ_QKV + 4 * 524288 + 77824 + 81920 + 16384 + 16384)
    return;

  {
    PrepArgs pa;
    pa.W[0] = Wq; pa.W[1] = Wk; pa.W[2] = Wv; pa.W[3] = Wo;
    pa.Wb[0] = Wqb; pa.Wb[1] = Wkb; pa.Wb[2] = Wvb; pa.Wb[3] = Wob;
    pa.pe = pe; pa.pe_b = pe_b; pa.peT1 = peT1; pa.peB = peB; pa.peBb = peBb;
    prep_all<<<1184, 256, 0, stream>>>(pa);
  }

  {
    GemmArgs ga;
    ga.X[0] = query; ga.X[1] = key; ga.X[2] = value;
    ga.W[0] = Wqb;   ga.W[1] = Wkb; ga.W[2] = Wvb;
    ga.bias[0] = bq; ga.bias[1] = bk; ga.bias[2] = bv;
    ga.scale[0] = ALPHA_Q; ga.scale[1] = 1.f; ga.scale[2] = 1.f;
    ga.Yb[0] = qbuf; ga.Yb[1] = kbuf; ga.Yb[2] = vbuf;
    ga.Yf = nullptr;
    gemm_nt<1><<<dim3(8, 64, 3), 512, 0, stream>>>(ga);
  }

  attn_mfma<<<1024, 256, 0, stream>>>(qbuf, kbuf, vbuf, pe_b, peT1, peB, peBb, pe, obuf);

  {
    GemmArgs ga;
    ga.X[0] = obuf; ga.X[1] = nullptr; ga.X[2] = nullptr;
    ga.W[0] = Wob;  ga.W[1] = nullptr; ga.W[2] = nullptr;
    ga.bias[0] = bo; ga.bias[1] = nullptr; ga.bias[2] = nullptr;
    ga.scale[0] = 1.f; ga.scale[1] = 1.f; ga.scale[2] = 1.f;
    ga.Yb[0] = nullptr; ga.Yb[1] = nullptr; ga.Yb[2] = nullptr;
    ga.Yf = (float*)d_out;
    gemm_nt<0><<<dim3(8, 64, 1), 512, 0, stream>>>(ga);
  }
}

// Round 13
// 173.726 us; speedup vs baseline: 1.1502x; 1.1502x over previous
//
#include <hip/hip_runtime.h>
#include <hip/hip_bf16.h>

typedef short bf16x8 __attribute__((ext_vector_type(8)));
typedef short bf16x4 __attribute__((ext_vector_type(4)));
typedef float f32x4 __attribute__((ext_vector_type(4)));

#define ALPHA_Q 0.1803368801111204f   // 0.125 * log2(e): softmax scale + exp2 base folded into q

static __device__ __forceinline__ unsigned short f2bf(float f) {
  unsigned u = __float_as_uint(f);
  u += 0x7fffu + ((u >> 16) & 1u);           // RNE
  return (unsigned short)(u >> 16);
}
static __device__ __forceinline__ float bf2f(unsigned short h) {
  return __uint_as_float((unsigned)h << 16);
}

// ---------------------------------------------------------------------------
// One prep kernel: 4x weight fp32->bf16 convert + pe table builds.
// ---------------------------------------------------------------------------
struct PrepArgs {
  const float* W[4];
  unsigned short* Wb[4];
  const float* pe;
  unsigned short *pe_b, *peT1, *peB, *peBb;
};

__global__ __launch_bounds__(256) void prep_all(PrepArgs pa) {
  const int bid = blockIdx.x;
  const int t = threadIdx.x;
  if (bid < 1024) {
    const int w = bid >> 8;
    const int i = ((bid & 255) << 8) + t;      // < 65536 float4s
    float4 v = ((const float4*)pa.W[w])[i];
    uint2 o;
    o.x = (unsigned)f2bf(v.x) | ((unsigned)f2bf(v.y) << 16);
    o.y = (unsigned)f2bf(v.z) | ((unsigned)f2bf(v.w) << 16);
    ((uint2*)pa.Wb[w])[i] = o;
  } else {
    const int i = ((bid - 1024) << 8) + t;     // < 40960
    const float* pe = pa.pe;
    if (i < 608 * 64) {
      int r = i >> 6, d = i & 63;
      pa.pe_b[i] = (r <= 512) ? f2bf(pe[r * 64 + d]) : (unsigned short)0;
    }
    if (i < 64 * 640) {
      int d = i / 640, y = i % 640;
      pa.peT1[i] = (y < 512) ? f2bf(pe[(y + 1) * 64 + d]) : (unsigned short)0;
    }
    if (i < 64 * 128) {
      int d = i >> 7, u = i & 127;
      pa.peB[i] = f2bf(pe[(u > 63 ? u - 63 : 0) * 64 + d]);
    }
    if (i < 128 * 64) {
      int v = i >> 6, d = i & 63;
      pa.peBb[i] = f2bf(pe[(v > 63 ? v - 63 : 0) * 64 + d]);
    }
  }
}

// ---------------------------------------------------------------------------
// NT GEMM via MFMA: Y[m][n] = (sum_k A[m][k]*W[n][k] + bias[n]) * scale
// ---------------------------------------------------------------------------
struct GemmArgs {
  const void* X[3];
  const unsigned short* W[3];
  const float* bias[3];
  float scale[3];
  unsigned short* Yb[3];
  float* Yf;
};

template<int AFP32>
__global__ __launch_bounds__(512) void gemm_nt(GemmArgs ga) {
  __shared__ __align__(16) unsigned short asb[2][128][72];
  __shared__ __align__(16) unsigned short bsb[2][64][72];
  const int z = blockIdx.z;
  const void* Xv = ga.X[z];
  const unsigned short* W = ga.W[z];
  const int t = threadIdx.x;
  const int wid = t >> 6, lane = t & 63;
  const int l15 = lane & 15, l4 = lane >> 4;
  const int n0 = blockIdx.x << 6, m0 = blockIdx.y << 7;
  const int wr0 = wid << 4;

  f32x4 acc[4];
#pragma unroll
  for (int j = 0; j < 4; ++j) acc[j] = (f32x4){0.f, 0.f, 0.f, 0.f};

  auto stage = [&](int k0, int buf) {
    if (AFP32) {
      const float* X = (const float*)Xv;
#pragma unroll
      for (int i = 0; i < 4; ++i) {
        int idx = t + (i << 9);
        int row = idx >> 4, c4 = (idx & 15) << 2;
        float4 v = *(const float4*)(X + (size_t)(m0 + row) * 512 + k0 + c4);
        uint2 o;
        o.x = (unsigned)f2bf(v.x) | ((unsigned)f2bf(v.y) << 16);
        o.y = (unsigned)f2bf(v.z) | ((unsigned)f2bf(v.w) << 16);
        *(uint2*)&asb[buf][row][c4] = o;
      }
    } else {
      const unsigned short* X = (const unsigned short*)Xv;
#pragma unroll
      for (int i = 0; i < 2; ++i) {
        int idx = t + (i << 9);
        int row = idx >> 3, g8 = (idx & 7) << 3;
        *(bf16x8*)&asb[buf][row][g8] = *(const bf16x8*)(X + (size_t)(m0 + row) * 512 + k0 + g8);
      }
    }
    int row = t >> 3, g8 = (t & 7) << 3;
    *(bf16x8*)&bsb[buf][row][g8] = *(const bf16x8*)(W + (size_t)(n0 + row) * 512 + k0 + g8);
  };

  stage(0, 0);
  __syncthreads();
  for (int it = 0; it < 8; ++it) {
    const int buf = it & 1;
    if (it < 7) stage((it + 1) << 6, buf ^ 1);
#pragma unroll
    for (int ks = 0; ks < 2; ++ks) {
      bf16x8 af = *(const bf16x8*)&asb[buf][wr0 + l15][(ks << 5) + (l4 << 3)];
#pragma unroll
      for (int j = 0; j < 4; ++j) {
        bf16x8 bw = *(const bf16x8*)&bsb[buf][(j << 4) + l15][(ks << 5) + (l4 << 3)];
        acc[j] = __builtin_amdgcn_mfma_f32_16x16x32_bf16(af, bw, acc[j], 0, 0, 0);
      }
    }
    __syncthreads();
  }

  const float* bias = ga.bias[z];
  const float scale = ga.scale[z];
#pragma unroll
  for (int j = 0; j < 4; ++j) {
    const int n = n0 + (j << 4) + l15;
    const float bn = bias[n];
#pragma unroll
    for (int r = 0; r < 4; ++r) {
      const int m = m0 + wr0 + (l4 << 2) + r;
      float v = (acc[j][r] + bn) * scale;
      if (AFP32) ga.Yb[z][(size_t)m * 512 + n] = f2bf(v);
      else       ga.Yf[(size_t)m * 512 + n] = v;
    }
  }
}

// ---------------------------------------------------------------------------
// Fused causal attention + relative terms. SWAPPED-QK (round-9 frame, 97.8us)
// + CU-balanced tile table (per-CU chunk sums uniform). 4 waves, 256 thr,
// 36.4 KB LDS, 1024 blocks, launch_bounds (256,3) -- NO tighter cap (spill!).
// ---------------------------------------------------------------------------
__global__ __launch_bounds__(256, 3) void attn_mfma(
    const unsigned short* __restrict__ qb,
    const unsigned short* __restrict__ kb,
    const unsigned short* __restrict__ vb,
    const unsigned short* __restrict__ pe_b,
    const unsigned short* __restrict__ peT1,
    const unsigned short* __restrict__ peB,
    const unsigned short* __restrict__ peBb,
    const float* __restrict__ pe,
    unsigned short* __restrict__ Oa) {
  const int bid = blockIdx.x;
  const int bh  = ((bid & 7) << 3) | ((bid >> 3) & 7);  // XCD-grouped (b = XCD)
  const int b = bh >> 3, h = bh & 7;
  // Balanced tile table: dispatch groups (bid>>8 = 0..3) get tiles
  // {15-a, 8+a, 4+a, 3-a} (a = (bid>>6)&3) -> per-CU sums uniform (30).
  const int w2 = bid >> 8, a2 = (bid >> 6) & 3;
  const int tile = (w2 == 0) ? (15 - a2) : (w2 == 1) ? (8 + a2)
                 : (w2 == 2) ? (4 + a2)  : (3 - a2);
  const int l0 = tile << 6;
  const int nch = tile + 1;

  const int t = threadIdx.x;
  const int wid = t >> 6, lane = t & 63;
  const int l15 = lane & 15, l4 = lane >> 4;
  const int wr0 = wid << 4;
  const int rowb = wr0 + (l4 << 2);
  const int qrow = wr0 + l15;            // swapped: this lane's q row
  const int lq = l0 + qrow;

  __shared__ __align__(16) char smem[36352];
  unsigned short (*ksb)[72]   = (unsigned short(*)[72])(smem);            //  9216 B
  unsigned short (*vtb)[72]   = (unsigned short(*)[72])(smem + 9216);     //  9216 B
  unsigned short (*band)[136] = (unsigned short(*)[136])(smem + 18432);   // 17408 B
  float* den_lds              = (float*)(smem + 35840);                   //   256 B
  float* pr0_lds              = (float*)(smem + 36096);                   //   256 B

  // zero band once; masked writes keep each row's complement zero forever
  {
    unsigned int* zp = (unsigned int*)&band[0][0];
#pragma unroll
    for (int i = 0; i < 17; ++i) zp[t + (i << 8)] = 0u;
  }

  // q fragments (pre-scaled by ALPHA_Q in projection)
  bf16x8 aq[2];
  {
    const unsigned short* qp_ = qb + (size_t)(b * 1024 + l0 + qrow) * 512 + h * 64 + (l4 << 3);
    aq[0] = *(const bf16x8*)qp_;
    aq[1] = *(const bf16x8*)(qp_ + 32);
  }

  // qa0 = q . pe[0] for this lane's qrow (register resident in swapped layout)
  float qa0;
  {
    float part = 0.f;
#pragma unroll
    for (int ks = 0; ks < 2; ++ks)
#pragma unroll
      for (int i = 0; i < 8; ++i)
        part += bf2f((unsigned short)aq[ks][i]) * pe[(ks << 5) + (l4 << 3) + i];
    part += __shfl_xor(part, 16, 64);
    part += __shfl_xor(part, 32, 64);
    qa0 = part;
  }

  f32x4 ov[4], ow[4];
#pragma unroll
  for (int f = 0; f < 4; ++f) {
    ov[f] = (f32x4){0.f, 0.f, 0.f, 0.f};
    ow[f] = (f32x4){0.f, 0.f, 0.f, 0.f};
  }
  float denT = 0.f, pr0T = 0.f;

  const int srow0 = t >> 3, sg = t & 7;
  bf16x8 kreg[2], vreg[2];
  auto LOADKV = [&](int cc) {
#pragma unroll
    for (int i = 0; i < 2; ++i) {
      const size_t ga = (size_t)(b * 1024 + (cc << 6) + srow0 + (i << 5)) * 512 + h * 64 + (sg << 3);
      kreg[i] = *(const bf16x8*)(kb + ga);
      vreg[i] = *(const bf16x8*)(vb + ga);
    }
  };
  auto WRITEKV = [&]() {
#pragma unroll
    for (int i = 0; i < 2; ++i) {
      const int row = srow0 + (i << 5);
      *(bf16x8*)&ksb[row][sg << 3] = kreg[i];
      const int col = (((row >> 3) ^ sg) << 3) + (row & 7);  // bank-uniform transpose
#pragma unroll
      for (int j = 0; j < 8; ++j)
        vtb[(sg << 3) + j][col] = (unsigned short)vreg[i][j];
    }
  };

  LOADKV(0);
  WRITEKV();
  __syncthreads();

  const int f8lo = 3 - wid;              // bias v-window per wave: [48-16w, 127-16w]
  const int k2lo = (wid < 2) ? 1 : 0;    // out-band: wave's zero k-slice skipped
  // bpermute source lanes for PV A-frag build (byte indices)
  const int src0 = (l15 + ((((l4 << 1) + 0) & 3) << 4)) << 2;
  const int src1 = (l15 + ((((l4 << 1) + 1) & 3) << 4)) << 2;
  const bool hi4 = (l4 >= 2);

  for (int c = 0; c < nch; ++c) {
    const int s0 = c << 6;
    const bool clipped = (c <= tile - 9);   // all s-l <= -512 -> pe row 0
    const bool bnd = (c == tile - 8);       // band straddles the clip point
    if (c + 1 < nch) LOADKV(c + 1);         // T14: issue early, write after barrier

    // ---- QK^T (swapped): sc[f][r] = S[s=s0+16f+4*l4+r][q=qrow] ----
    f32x4 sc[4];
#pragma unroll
    for (int f = 0; f < 4; ++f) sc[f] = (f32x4){0.f, 0.f, 0.f, 0.f};
    __builtin_amdgcn_s_setprio(1);
#pragma unroll
    for (int ks = 0; ks < 2; ++ks)
#pragma unroll
      for (int f = 0; f < 4; ++f) {
        bf16x8 bk = *(const bf16x8*)&ksb[(f << 4) + l15][(ks << 5) + (l4 << 3)];
        sc[f] = __builtin_amdgcn_mfma_f32_16x16x32_bf16(bk, aq[ks], sc[f], 0, 0, 0);
      }
    __builtin_amdgcn_s_setprio(0);

    // ---- transposed bias GEMM: D[v][qrow] = pe[v+voff].q, B-frags INLINE ----
    if (!clipped) {
      const unsigned short* bsrcB = bnd ? peBb : (pe_b + (size_t)(s0 - l0 + 449) * 64);
      f32x4 macc[5];
#pragma unroll
      for (int i = 0; i < 5; ++i) macc[i] = (f32x4){0.f, 0.f, 0.f, 0.f};
      __builtin_amdgcn_s_setprio(1);
#pragma unroll
      for (int i = 0; i < 5; ++i) {
        const unsigned short* p_ = bsrcB + (size_t)(((f8lo + i) << 4) + l15) * 64 + (l4 << 3);
        bf16x8 bp0 = *(const bf16x8*)p_;
        bf16x8 bp1 = *(const bf16x8*)(p_ + 32);
        macc[i] = __builtin_amdgcn_mfma_f32_16x16x32_bf16(bp0, aq[0], macc[i], 0, 0, 0);
        macc[i] = __builtin_amdgcn_mfma_f32_16x16x32_bf16(bp1, aq[1], macc[i], 0, 0, 0);
      }
      __builtin_amdgcn_s_setprio(0);
      const int Aw = 63 - qrow, Bw = 126 - qrow;   // row's valid u window
#pragma unroll
      for (int i = 0; i < 5; ++i) {
        const int v0 = ((f8lo + i) << 4) + (l4 << 2);
        if (v0 >= Aw && v0 + 3 <= Bw) {
          bf16x4 pk;
#pragma unroll
          for (int r = 0; r < 4; ++r) pk[r] = (short)f2bf(macc[i][r]);
          *(bf16x4*)&band[qrow][v0] = pk;
        } else if (v0 + 3 >= Aw && v0 <= Bw) {
#pragma unroll
          for (int r = 0; r < 4; ++r) {
            const int v = v0 + r;
            if (v >= Aw && v <= Bw) band[qrow][v] = f2bf(macc[i][r]);
          }
        }
      }
    }

    // ---- P-phase (swapped): bias from band at (qrow,u), exp2, pack P ----
    unsigned int dw[4][2];
#pragma unroll
    for (int f = 0; f < 4; ++f) {
#pragma unroll
      for (int h2 = 0; h2 < 2; ++h2) {
        unsigned int dword = 0;
#pragma unroll
        for (int rr = 0; rr < 2; ++rr) {
          const int r = (h2 << 1) + rr;
          const int slocal = (f << 4) + (l4 << 2) + r;
          const int s = s0 + slocal;
          const int u = slocal + 63 - qrow;
          const float qa = clipped ? qa0 : bf2f(band[qrow][u]);
          float p = exp2f(sc[f][r] + qa);
          p = (s <= lq) ? p : 0.f;
          denT += p;
          const unsigned short pbf = f2bf(p);
          if (!clipped) band[qrow][u] = pbf;
          else pr0T += p;
          dword |= ((unsigned)pbf) << (rr << 4);
        }
        dw[f][h2] = dword;
      }
    }

    // ---- PV: build A-frags in-register (bpermute across l4 group) ----
    __builtin_amdgcn_s_setprio(1);
#pragma unroll
    for (int ks = 0; ks < 2; ++ks) {
      const int flo = ks << 1, fhi = flo + 1;
      int a0lo = __builtin_amdgcn_ds_bpermute(src0, (int)dw[flo][0]);
      int a0hi = __builtin_amdgcn_ds_bpermute(src0, (int)dw[fhi][0]);
      int a1lo = __builtin_amdgcn_ds_bpermute(src0, (int)dw[flo][1]);
      int a1hi = __builtin_amdgcn_ds_bpermute(src0, (int)dw[fhi][1]);
      int a2lo = __builtin_amdgcn_ds_bpermute(src1, (int)dw[flo][0]);
      int a2hi = __builtin_amdgcn_ds_bpermute(src1, (int)dw[fhi][0]);
      int a3lo = __builtin_amdgcn_ds_bpermute(src1, (int)dw[flo][1]);
      int a3hi = __builtin_amdgcn_ds_bpermute(src1, (int)dw[fhi][1]);
      union { int i4[4]; bf16x8 v8; } au;
      au.i4[0] = hi4 ? a0hi : a0lo;
      au.i4[1] = hi4 ? a1hi : a1lo;
      au.i4[2] = hi4 ? a2hi : a2lo;
      au.i4[3] = hi4 ? a3hi : a3lo;
#pragma unroll
      for (int f = 0; f < 4; ++f) {
        const int d = (f << 4) + l15;
        const int U = ((ks << 2) + l4) ^ ((d >> 3) & 7);
        bf16x8 bv = *(const bf16x8*)&vtb[d][U << 3];
        ov[f] = __builtin_amdgcn_mfma_f32_16x16x32_bf16(au.v8, bv, ov[f], 0, 0, 0);
      }
    }
    __builtin_amdgcn_s_setprio(0);

    __syncthreads();                 // all waves done with ksb/vtb
    if (c + 1 < nch) WRITEKV();

    // ---- out-band GEMM: ow += peW . band (3 k-slices, A-frags INLINE) ----
    if (!clipped) {
      const unsigned short* asrc = bnd ? peB : (peT1 + (s0 - l0 + 448));
      const int astr = bnd ? 128 : 640;
      bf16x8 bb[3];
#pragma unroll
      for (int k = 0; k < 3; ++k)
        bb[k] = *(const bf16x8*)&band[wr0 + l15][((k2lo + k) << 5) + (l4 << 3)];
      __builtin_amdgcn_s_setprio(1);
#pragma unroll
      for (int fd = 0; fd < 4; ++fd)
#pragma unroll
        for (int k = 0; k < 3; ++k) {
          bf16x8 af = *(const bf16x8*)(asrc + (size_t)((fd << 4) + l15) * astr + ((k2lo + k) << 5) + (l4 << 3));
          ow[fd] = __builtin_amdgcn_mfma_f32_16x16x32_bf16(af, bb[k], ow[fd], 0, 0, 0);
        }
      __builtin_amdgcn_s_setprio(0);
    }
    __syncthreads();                 // staged K/V visible; band free next chunk
  }

  // ---- publish den/pr0 per q-row (reduce over l4 group; wave-private LDS) ----
  denT += __shfl_xor(denT, 16, 64);
  denT += __shfl_xor(denT, 32, 64);
  pr0T += __shfl_xor(pr0T, 16, 64);
  pr0T += __shfl_xor(pr0T, 32, 64);
  if (l4 == 0) {
    den_lds[qrow] = denT;
    pr0_lds[qrow] = pr0T;
  }
  float den_j[4], pr0_j[4];
#pragma unroll
  for (int j = 0; j < 4; ++j) {
    den_j[j] = den_lds[rowb + j];
    pr0_j[j] = pr0_lds[rowb + j];
  }

  // clipped-region contribution: pr0 * pe[0][d]
#pragma unroll
  for (int f = 0; f < 4; ++f) {
    const float pe0 = pe[(f << 4) + l15];
#pragma unroll
    for (int j = 0; j < 4; ++j) ov[f][j] += pr0_j[j] * pe0;
  }

  // ---- transpose ow in the wave's PRIVATE band rows (wave-synchronous) ----
  float (*tbw)[17] = (float(*)[17])&band[wr0][0];   // 16 rows * 272 B = [64][17] f32
#pragma unroll
  for (int fd = 0; fd < 4; ++fd)
#pragma unroll
    for (int r = 0; r < 4; ++r)
      tbw[(fd << 4) + (l4 << 2) + r][l15] = ow[fd][r];

  // ---- normalize + store bf16 ----
#pragma unroll
  for (int j = 0; j < 4; ++j) {
    const float inv = 1.f / den_j[j];
    unsigned short* dst = Oa + (size_t)(b * 1024 + l0 + rowb + j) * 512 + h * 64;
#pragma unroll
    for (int f = 0; f < 4; ++f) {
      const float o2 = tbw[(f << 4) + l15][(l4 << 2) + j];
      dst[(f << 4) + l15] = f2bf((ov[f][j] + o2) * inv);
    }
  }
}

// ---------------------------------------------------------------------------
extern "C" void kernel_launch(void* const* d_in, const int* in_sizes, int n_in,
                              void* d_out, int out_size, void* d_ws, size_t ws_size,
                              hipStream_t stream) {
  const float* query = (const float*)d_in[0];
  const float* key   = (const float*)d_in[1];
  const float* value = (const float*)d_in[2];
  // d_in[3] attention_mask == 1 -> causal
  const float* Wq = (const float*)d_in[4];
  const float* bq = (const float*)d_in[5];
  const float* Wk = (const float*)d_in[6];
  const float* bk = (const float*)d_in[7];
  const float* Wv = (const float*)d_in[8];
  const float* bv = (const float*)d_in[9];
  const float* pe = (const float*)d_in[10];
  const float* Wo = (const float*)d_in[11];
  const float* bo = (const float*)d_in[12];

  char* ws = (char*)d_ws;
  const size_t SZ_QKV = (size_t)8192 * 512 * 2;           // 8,388,608
  unsigned short* qbuf = (unsigned short*)(ws);
  unsigned short* kbuf = (unsigned short*)(ws + SZ_QKV);
  unsigned short* vbuf = (unsigned short*)(ws + 2 * SZ_QKV);
  unsigned short* obuf = (unsigned short*)(ws + 3 * SZ_QKV);
  char* wbase = ws + 4 * SZ_QKV;
  unsigned short* Wqb  = (unsigned short*)(wbase);
  unsigned short* Wkb  = (unsigned short*)(wbase + 524288);
  unsigned short* Wvb  = (unsigned short*)(wbase + 2 * 524288);
  unsigned short* Wob  = (unsigned short*)(wbase + 3 * 524288);
  unsigned short* pe_b = (unsigned short*)(wbase + 4 * 524288);
  unsigned short* peT1 = (unsigned short*)(wbase + 4 * 524288 + 77824);
  unsigned short* peB  = (unsigned short*)(wbase + 4 * 524288 + 77824 + 81920);
  unsigned short* peBb = (unsigned short*)(wbase + 4 * 524288 + 77824 + 81920 + 16384);
  if (ws_size < (size_t)4 * SZ_QKV + 4 * 524288 + 77824 + 81920 + 16384 + 16384)
    return;

  {
    PrepArgs pa;
    pa.W[0] = Wq; pa.W[1] = Wk; pa.W[2] = Wv; pa.W[3] = Wo;
    pa.Wb[0] = Wqb; pa.Wb[1] = Wkb; pa.Wb[2] = Wvb; pa.Wb[3] = Wob;
    pa.pe = pe; pa.pe_b = pe_b; pa.peT1 = peT1; pa.peB = peB; pa.peBb = peBb;
    prep_all<<<1184, 256, 0, stream>>>(pa);
  }

  {
    GemmArgs ga;
    ga.X[0] = query; ga.X[1] = key; ga.X[2] = value;
    ga.W[0] = Wqb;   ga.W[1] = Wkb; ga.W[2] = Wvb;
    ga.bias[0] = bq; ga.bias[1] = bk; ga.bias[2] = bv;
    ga.scale[0] = ALPHA_Q; ga.scale[1] = 1.f; ga.scale[2] = 1.f;
    ga.Yb[0] = qbuf; ga.Yb[1] = kbuf; ga.Yb[2] = vbuf;
    ga.Yf = nullptr;
    gemm_nt<1><<<dim3(8, 64, 3), 512, 0, stream>>>(ga);
  }

  attn_mfma<<<1024, 256, 0, stream>>>(qbuf, kbuf, vbuf, pe_b, peT1, peB, peBb, pe, obuf);

  {
    GemmArgs ga;
    ga.X[0] = obuf; ga.X[1] = nullptr; ga.X[2] = nullptr;
    ga.W[0] = Wob;  ga.W[1] = nullptr; ga.W[2] = nullptr;
    ga.bias[0] = bo; ga.bias[1] = nullptr; ga.bias[2] = nullptr;
    ga.scale[0] = 1.f; ga.scale[1] = 1.f; ga.scale[2] = 1.f;
    ga.Yb[0] = nullptr; ga.Yb[1] = nullptr; ga.Yb[2] = nullptr;
    ga.Yf = (float*)d_out;
    gemm_nt<0><<<dim3(8, 64, 1), 512, 0, stream>>>(ga);
  }
}

// Round 14
// 145.104 us; speedup vs baseline: 1.3771x; 1.1972x over previous
//
#include <hip/hip_runtime.h>
#include <hip/hip_bf16.h>

typedef short bf16x8 __attribute__((ext_vector_type(8)));
typedef short bf16x4 __attribute__((ext_vector_type(4)));
typedef float f32x4 __attribute__((ext_vector_type(4)));

#define ALPHA_Q 0.1803368801111204f   // 0.125 * log2(e): softmax scale + exp2 base folded into q

static __device__ __forceinline__ unsigned short f2bf(float f) {
  unsigned u = __float_as_uint(f);
  u += 0x7fffu + ((u >> 16) & 1u);           // RNE
  return (unsigned short)(u >> 16);
}
static __device__ __forceinline__ float bf2f(unsigned short h) {
  return __uint_as_float((unsigned)h << 16);
}

// ---------------------------------------------------------------------------
// One prep kernel: X (q/k/v inputs) fp32->bf16, 4x weight fp32->bf16,
// pe table builds. Grid = 12288 (X) + 1024 (W) + 160 (pe) = 13472 blocks.
// ---------------------------------------------------------------------------
struct PrepArgs {
  const float* W[4];
  unsigned short* Wb[4];
  const float* X[3];
  unsigned short* Xb[3];
  const float* pe;
  unsigned short *pe_b, *peT1, *peB, *peBb;
};

__global__ __launch_bounds__(256) void prep_all(PrepArgs pa) {
  const int bid = blockIdx.x;
  const int t = threadIdx.x;
  if (bid < 12288) {
    const int w = bid >> 12;                   // 0..2
    const int i = ((bid & 4095) << 8) + t;     // < 1,048,576 float4s
    float4 v = ((const float4*)pa.X[w])[i];
    uint2 o;
    o.x = (unsigned)f2bf(v.x) | ((unsigned)f2bf(v.y) << 16);
    o.y = (unsigned)f2bf(v.z) | ((unsigned)f2bf(v.w) << 16);
    ((uint2*)pa.Xb[w])[i] = o;
  } else if (bid < 13312) {
    const int b2 = bid - 12288;
    const int w = b2 >> 8;
    const int i = ((b2 & 255) << 8) + t;       // < 65536 float4s
    float4 v = ((const float4*)pa.W[w])[i];
    uint2 o;
    o.x = (unsigned)f2bf(v.x) | ((unsigned)f2bf(v.y) << 16);
    o.y = (unsigned)f2bf(v.z) | ((unsigned)f2bf(v.w) << 16);
    ((uint2*)pa.Wb[w])[i] = o;
  } else {
    const int i = ((bid - 13312) << 8) + t;    // < 40960
    const float* pe = pa.pe;
    if (i < 608 * 64) {
      int r = i >> 6, d = i & 63;
      pa.pe_b[i] = (r <= 512) ? f2bf(pe[r * 64 + d]) : (unsigned short)0;
    }
    if (i < 64 * 640) {
      int d = i / 640, y = i % 640;
      pa.peT1[i] = (y < 512) ? f2bf(pe[(y + 1) * 64 + d]) : (unsigned short)0;
    }
    if (i < 64 * 128) {
      int d = i >> 7, u = i & 127;
      pa.peB[i] = f2bf(pe[(u > 63 ? u - 63 : 0) * 64 + d]);
    }
    if (i < 128 * 64) {
      int v = i >> 6, d = i & 63;
      pa.peBb[i] = f2bf(pe[(v > 63 ? v - 63 : 0) * 64 + d]);
    }
  }
}

// ---------------------------------------------------------------------------
// NT GEMM via MFMA, pure bf16 staging: Y[m][n] = (A[m][:].W[n][:] + bias)*scale
// BM=BN=128, BK=64, 256 thr / 4 waves (2x2 of 64x64), 32 MFMA per wave-iter
// vs 16 ds_read_b128 (2:1). T14 reg-staged single-buffer LDS [128][72].
// ---------------------------------------------------------------------------
struct GemmArgs {
  const unsigned short* A[3];
  const unsigned short* W[3];
  const float* bias[3];
  float scale[3];
  unsigned short* Yb[3];
  float* Yf;
};

template<int F32OUT>
__global__ __launch_bounds__(256) void gemm128(GemmArgs ga) {
  __shared__ __align__(16) unsigned short asb[128][72];
  __shared__ __align__(16) unsigned short bsb[128][72];
  const int z = blockIdx.z;
  const unsigned short* A = ga.A[z];
  const unsigned short* W = ga.W[z];
  const int t = threadIdx.x;
  const int lane = t & 63;
  const int l15 = lane & 15, l4 = lane >> 4;
  const int wid = t >> 6;
  const int wr = (wid >> 1) << 6, wc = (wid & 1) << 6;
  const int n0 = blockIdx.x << 7, m0 = blockIdx.y << 7;

  f32x4 acc[4][4];
#pragma unroll
  for (int i = 0; i < 4; ++i)
#pragma unroll
    for (int j = 0; j < 4; ++j) acc[i][j] = (f32x4){0.f, 0.f, 0.f, 0.f};

  const int srow = t >> 3, scol = (t & 7) << 3;
  bf16x8 ar[4], br[4];
  auto LOAD = [&](int k0) {
#pragma unroll
    for (int i = 0; i < 4; ++i) {
      const int row = srow + (i << 5);
      ar[i] = *(const bf16x8*)(A + (size_t)(m0 + row) * 512 + k0 + scol);
      br[i] = *(const bf16x8*)(W + (size_t)(n0 + row) * 512 + k0 + scol);
    }
  };
  auto WRITE = [&]() {
#pragma unroll
    for (int i = 0; i < 4; ++i) {
      const int row = srow + (i << 5);
      *(bf16x8*)&asb[row][scol] = ar[i];
      *(bf16x8*)&bsb[row][scol] = br[i];
    }
  };

  LOAD(0);
  WRITE();
  __syncthreads();
  for (int it = 0; it < 8; ++it) {
    if (it < 7) LOAD((it + 1) << 6);   // T14: issue next-tile loads early
#pragma unroll
    for (int ks = 0; ks < 2; ++ks) {
      bf16x8 af[4], bw[4];
#pragma unroll
      for (int i = 0; i < 4; ++i)
        af[i] = *(const bf16x8*)&asb[wr + (i << 4) + l15][(ks << 5) + (l4 << 3)];
#pragma unroll
      for (int j = 0; j < 4; ++j)
        bw[j] = *(const bf16x8*)&bsb[wc + (j << 4) + l15][(ks << 5) + (l4 << 3)];
#pragma unroll
      for (int i = 0; i < 4; ++i)
#pragma unroll
        for (int j = 0; j < 4; ++j)
          acc[i][j] = __builtin_amdgcn_mfma_f32_16x16x32_bf16(af[i], bw[j], acc[i][j], 0, 0, 0);
    }
    __syncthreads();                   // all waves done reading LDS
    if (it < 7) {
      WRITE();
      __syncthreads();                 // staged tile visible
    }
  }

  const float* bias = ga.bias[z];
  const float scale = ga.scale[z];
#pragma unroll
  for (int j = 0; j < 4; ++j) {
    const int n = n0 + wc + (j << 4) + l15;
    const float bn = bias[n];
#pragma unroll
    for (int i = 0; i < 4; ++i) {
#pragma unroll
      for (int r = 0; r < 4; ++r) {
        const int m = m0 + wr + (i << 4) + (l4 << 2) + r;
        float v = (acc[i][j][r] + bn) * scale;
        if (F32OUT) ga.Yf[(size_t)m * 512 + n] = v;
        else        ga.Yb[z][(size_t)m * 512 + n] = f2bf(v);
      }
    }
  }
}

// ---------------------------------------------------------------------------
// Fused causal attention + relative terms. SWAPPED-QK (round-13, ~98 us):
// Block = (b,h, 64 q-rows), 4 waves, 256 thr, 36.4 KB LDS, 1024 blocks,
// balanced tile table, launch_bounds (256,3). UNCHANGED.
// ---------------------------------------------------------------------------
__global__ __launch_bounds__(256, 3) void attn_mfma(
    const unsigned short* __restrict__ qb,
    const unsigned short* __restrict__ kb,
    const unsigned short* __restrict__ vb,
    const unsigned short* __restrict__ pe_b,
    const unsigned short* __restrict__ peT1,
    const unsigned short* __restrict__ peB,
    const unsigned short* __restrict__ peBb,
    const float* __restrict__ pe,
    unsigned short* __restrict__ Oa) {
  const int bid = blockIdx.x;
  const int bh  = ((bid & 7) << 3) | ((bid >> 3) & 7);  // XCD-grouped (b = XCD)
  const int b = bh >> 3, h = bh & 7;
  const int w2 = bid >> 8, a2 = (bid >> 6) & 3;
  const int tile = (w2 == 0) ? (15 - a2) : (w2 == 1) ? (8 + a2)
                 : (w2 == 2) ? (4 + a2)  : (3 - a2);
  const int l0 = tile << 6;
  const int nch = tile + 1;

  const int t = threadIdx.x;
  const int wid = t >> 6, lane = t & 63;
  const int l15 = lane & 15, l4 = lane >> 4;
  const int wr0 = wid << 4;
  const int rowb = wr0 + (l4 << 2);
  const int qrow = wr0 + l15;            // swapped: this lane's q row
  const int lq = l0 + qrow;

  __shared__ __align__(16) char smem[36352];
  unsigned short (*ksb)[72]   = (unsigned short(*)[72])(smem);            //  9216 B
  unsigned short (*vtb)[72]   = (unsigned short(*)[72])(smem + 9216);     //  9216 B
  unsigned short (*band)[136] = (unsigned short(*)[136])(smem + 18432);   // 17408 B
  float* den_lds              = (float*)(smem + 35840);                   //   256 B
  float* pr0_lds              = (float*)(smem + 36096);                   //   256 B

  {
    unsigned int* zp = (unsigned int*)&band[0][0];
#pragma unroll
    for (int i = 0; i < 17; ++i) zp[t + (i << 8)] = 0u;
  }

  bf16x8 aq[2];
  {
    const unsigned short* qp_ = qb + (size_t)(b * 1024 + l0 + qrow) * 512 + h * 64 + (l4 << 3);
    aq[0] = *(const bf16x8*)qp_;
    aq[1] = *(const bf16x8*)(qp_ + 32);
  }

  float qa0;
  {
    float part = 0.f;
#pragma unroll
    for (int ks = 0; ks < 2; ++ks)
#pragma unroll
      for (int i = 0; i < 8; ++i)
        part += bf2f((unsigned short)aq[ks][i]) * pe[(ks << 5) + (l4 << 3) + i];
    part += __shfl_xor(part, 16, 64);
    part += __shfl_xor(part, 32, 64);
    qa0 = part;
  }

  f32x4 ov[4], ow[4];
#pragma unroll
  for (int f = 0; f < 4; ++f) {
    ov[f] = (f32x4){0.f, 0.f, 0.f, 0.f};
    ow[f] = (f32x4){0.f, 0.f, 0.f, 0.f};
  }
  float denT = 0.f, pr0T = 0.f;

  const int srow0 = t >> 3, sg = t & 7;
  bf16x8 kreg[2], vreg[2];
  auto LOADKV = [&](int cc) {
#pragma unroll
    for (int i = 0; i < 2; ++i) {
      const size_t ga = (size_t)(b * 1024 + (cc << 6) + srow0 + (i << 5)) * 512 + h * 64 + (sg << 3);
      kreg[i] = *(const bf16x8*)(kb + ga);
      vreg[i] = *(const bf16x8*)(vb + ga);
    }
  };
  auto WRITEKV = [&]() {
#pragma unroll
    for (int i = 0; i < 2; ++i) {
      const int row = srow0 + (i << 5);
      *(bf16x8*)&ksb[row][sg << 3] = kreg[i];
      const int col = (((row >> 3) ^ sg) << 3) + (row & 7);  // bank-uniform transpose
#pragma unroll
      for (int j = 0; j < 8; ++j)
        vtb[(sg << 3) + j][col] = (unsigned short)vreg[i][j];
    }
  };

  LOADKV(0);
  WRITEKV();
  __syncthreads();

  const int f8lo = 3 - wid;              // bias v-window per wave: [48-16w, 127-16w]
  const int k2lo = (wid < 2) ? 1 : 0;    // out-band: wave's zero k-slice skipped
  const int src0 = (l15 + ((((l4 << 1) + 0) & 3) << 4)) << 2;
  const int src1 = (l15 + ((((l4 << 1) + 1) & 3) << 4)) << 2;
  const bool hi4 = (l4 >= 2);

  for (int c = 0; c < nch; ++c) {
    const int s0 = c << 6;
    const bool clipped = (c <= tile - 9);   // all s-l <= -512 -> pe row 0
    const bool bnd = (c == tile - 8);       // band straddles the clip point
    if (c + 1 < nch) LOADKV(c + 1);         // T14: issue early, write after barrier

    // ---- QK^T (swapped): sc[f][r] = S[s=s0+16f+4*l4+r][q=qrow] ----
    f32x4 sc[4];
#pragma unroll
    for (int f = 0; f < 4; ++f) sc[f] = (f32x4){0.f, 0.f, 0.f, 0.f};
    __builtin_amdgcn_s_setprio(1);
#pragma unroll
    for (int ks = 0; ks < 2; ++ks)
#pragma unroll
      for (int f = 0; f < 4; ++f) {
        bf16x8 bk = *(const bf16x8*)&ksb[(f << 4) + l15][(ks << 5) + (l4 << 3)];
        sc[f] = __builtin_amdgcn_mfma_f32_16x16x32_bf16(bk, aq[ks], sc[f], 0, 0, 0);
      }
    __builtin_amdgcn_s_setprio(0);

    // ---- transposed bias GEMM: D[v][qrow] = pe[v+voff].q, B-frags INLINE ----
    if (!clipped) {
      const unsigned short* bsrcB = bnd ? peBb : (pe_b + (size_t)(s0 - l0 + 449) * 64);
      f32x4 macc[5];
#pragma unroll
      for (int i = 0; i < 5; ++i) macc[i] = (f32x4){0.f, 0.f, 0.f, 0.f};
      __builtin_amdgcn_s_setprio(1);
#pragma unroll
      for (int i = 0; i < 5; ++i) {
        const unsigned short* p_ = bsrcB + (size_t)(((f8lo + i) << 4) + l15) * 64 + (l4 << 3);
        bf16x8 bp0 = *(const bf16x8*)p_;
        bf16x8 bp1 = *(const bf16x8*)(p_ + 32);
        macc[i] = __builtin_amdgcn_mfma_f32_16x16x32_bf16(bp0, aq[0], macc[i], 0, 0, 0);
        macc[i] = __builtin_amdgcn_mfma_f32_16x16x32_bf16(bp1, aq[1], macc[i], 0, 0, 0);
      }
      __builtin_amdgcn_s_setprio(0);
      const int Aw = 63 - qrow, Bw = 126 - qrow;   // row's valid u window
#pragma unroll
      for (int i = 0; i < 5; ++i) {
        const int v0 = ((f8lo + i) << 4) + (l4 << 2);
        if (v0 >= Aw && v0 + 3 <= Bw) {
          bf16x4 pk;
#pragma unroll
          for (int r = 0; r < 4; ++r) pk[r] = (short)f2bf(macc[i][r]);
          *(bf16x4*)&band[qrow][v0] = pk;
        } else if (v0 + 3 >= Aw && v0 <= Bw) {
#pragma unroll
          for (int r = 0; r < 4; ++r) {
            const int v = v0 + r;
            if (v >= Aw && v <= Bw) band[qrow][v] = f2bf(macc[i][r]);
          }
        }
      }
    }

    // ---- P-phase (swapped): bias from band at (qrow,u), exp2, pack P ----
    unsigned int dw[4][2];
#pragma unroll
    for (int f = 0; f < 4; ++f) {
#pragma unroll
      for (int h2 = 0; h2 < 2; ++h2) {
        unsigned int dword = 0;
#pragma unroll
        for (int rr = 0; rr < 2; ++rr) {
          const int r = (h2 << 1) + rr;
          const int slocal = (f << 4) + (l4 << 2) + r;
          const int s = s0 + slocal;
          const int u = slocal + 63 - qrow;
          const float qa = clipped ? qa0 : bf2f(band[qrow][u]);
          float p = exp2f(sc[f][r] + qa);
          p = (s <= lq) ? p : 0.f;
          denT += p;
          const unsigned short pbf = f2bf(p);
          if (!clipped) band[qrow][u] = pbf;
          else pr0T += p;
          dword |= ((unsigned)pbf) << (rr << 4);
        }
        dw[f][h2] = dword;
      }
    }

    // ---- PV: build A-frags in-register (bpermute across l4 group) ----
    __builtin_amdgcn_s_setprio(1);
#pragma unroll
    for (int ks = 0; ks < 2; ++ks) {
      const int flo = ks << 1, fhi = flo + 1;
      int a0lo = __builtin_amdgcn_ds_bpermute(src0, (int)dw[flo][0]);
      int a0hi = __builtin_amdgcn_ds_bpermute(src0, (int)dw[fhi][0]);
      int a1lo = __builtin_amdgcn_ds_bpermute(src0, (int)dw[flo][1]);
      int a1hi = __builtin_amdgcn_ds_bpermute(src0, (int)dw[fhi][1]);
      int a2lo = __builtin_amdgcn_ds_bpermute(src1, (int)dw[flo][0]);
      int a2hi = __builtin_amdgcn_ds_bpermute(src1, (int)dw[fhi][0]);
      int a3lo = __builtin_amdgcn_ds_bpermute(src1, (int)dw[flo][1]);
      int a3hi = __builtin_amdgcn_ds_bpermute(src1, (int)dw[fhi][1]);
      union { int i4[4]; bf16x8 v8; } au;
      au.i4[0] = hi4 ? a0hi : a0lo;
      au.i4[1] = hi4 ? a1hi : a1lo;
      au.i4[2] = hi4 ? a2hi : a2lo;
      au.i4[3] = hi4 ? a3hi : a3lo;
#pragma unroll
      for (int f = 0; f < 4; ++f) {
        const int d = (f << 4) + l15;
        const int U = ((ks << 2) + l4) ^ ((d >> 3) & 7);
        bf16x8 bv = *(const bf16x8*)&vtb[d][U << 3];
        ov[f] = __builtin_amdgcn_mfma_f32_16x16x32_bf16(au.v8, bv, ov[f], 0, 0, 0);
      }
    }
    __builtin_amdgcn_s_setprio(0);

    __syncthreads();                 // all waves done with ksb/vtb
    if (c + 1 < nch) WRITEKV();

    // ---- out-band GEMM: ow += peW . band (3 k-slices, A-frags INLINE) ----
    if (!clipped) {
      const unsigned short* asrc = bnd ? peB : (peT1 + (s0 - l0 + 448));
      const int astr = bnd ? 128 : 640;
      bf16x8 bb[3];
#pragma unroll
      for (int k = 0; k < 3; ++k)
        bb[k] = *(const bf16x8*)&band[wr0 + l15][((k2lo + k) << 5) + (l4 << 3)];
      __builtin_amdgcn_s_setprio(1);
#pragma unroll
      for (int fd = 0; fd < 4; ++fd)
#pragma unroll
        for (int k = 0; k < 3; ++k) {
          bf16x8 af = *(const bf16x8*)(asrc + (size_t)((fd << 4) + l15) * astr + ((k2lo + k) << 5) + (l4 << 3));
          ow[fd] = __builtin_amdgcn_mfma_f32_16x16x32_bf16(af, bb[k], ow[fd], 0, 0, 0);
        }
      __builtin_amdgcn_s_setprio(0);
    }
    __syncthreads();                 // staged K/V visible; band free next chunk
  }

  // ---- publish den/pr0 per q-row (reduce over l4 group; wave-private LDS) ----
  denT += __shfl_xor(denT, 16, 64);
  denT += __shfl_xor(denT, 32, 64);
  pr0T += __shfl_xor(pr0T, 16, 64);
  pr0T += __shfl_xor(pr0T, 32, 64);
  if (l4 == 0) {
    den_lds[qrow] = denT;
    pr0_lds[qrow] = pr0T;
  }
  float den_j[4], pr0_j[4];
#pragma unroll
  for (int j = 0; j < 4; ++j) {
    den_j[j] = den_lds[rowb + j];
    pr0_j[j] = pr0_lds[rowb + j];
  }

  // clipped-region contribution: pr0 * pe[0][d]
#pragma unroll
  for (int f = 0; f < 4; ++f) {
    const float pe0 = pe[(f << 4) + l15];
#pragma unroll
    for (int j = 0; j < 4; ++j) ov[f][j] += pr0_j[j] * pe0;
  }

  // ---- transpose ow in the wave's PRIVATE band rows (wave-synchronous) ----
  float (*tbw)[17] = (float(*)[17])&band[wr0][0];   // 16 rows * 272 B = [64][17] f32
#pragma unroll
  for (int fd = 0; fd < 4; ++fd)
#pragma unroll
    for (int r = 0; r < 4; ++r)
      tbw[(fd << 4) + (l4 << 2) + r][l15] = ow[fd][r];

  // ---- normalize + store bf16 ----
#pragma unroll
  for (int j = 0; j < 4; ++j) {
    const float inv = 1.f / den_j[j];
    unsigned short* dst = Oa + (size_t)(b * 1024 + l0 + rowb + j) * 512 + h * 64;
#pragma unroll
    for (int f = 0; f < 4; ++f) {
      const float o2 = tbw[(f << 4) + l15][(l4 << 2) + j];
      dst[(f << 4) + l15] = f2bf((ov[f][j] + o2) * inv);
    }
  }
}

// ---------------------------------------------------------------------------
extern "C" void kernel_launch(void* const* d_in, const int* in_sizes, int n_in,
                              void* d_out, int out_size, void* d_ws, size_t ws_size,
                              hipStream_t stream) {
  const float* query = (const float*)d_in[0];
  const float* key   = (const float*)d_in[1];
  const float* value = (const float*)d_in[2];
  // d_in[3] attention_mask == 1 -> causal
  const float* Wq = (const float*)d_in[4];
  const float* bq = (const float*)d_in[5];
  const float* Wk = (const float*)d_in[6];
  const float* bk = (const float*)d_in[7];
  const float* Wv = (const float*)d_in[8];
  const float* bv = (const float*)d_in[9];
  const float* pe = (const float*)d_in[10];
  const float* Wo = (const float*)d_in[11];
  const float* bo = (const float*)d_in[12];

  char* ws = (char*)d_ws;
  const size_t SZ_QKV = (size_t)8192 * 512 * 2;           // 8,388,608
  unsigned short* qbuf = (unsigned short*)(ws);
  unsigned short* kbuf = (unsigned short*)(ws + SZ_QKV);
  unsigned short* vbuf = (unsigned short*)(ws + 2 * SZ_QKV);
  unsigned short* obuf = (unsigned short*)(ws + 3 * SZ_QKV);
  char* wbase = ws + 4 * SZ_QKV;
  unsigned short* Wqb  = (unsigned short*)(wbase);
  unsigned short* Wkb  = (unsigned short*)(wbase + 524288);
  unsigned short* Wvb  = (unsigned short*)(wbase + 2 * 524288);
  unsigned short* Wob  = (unsigned short*)(wbase + 3 * 524288);
  unsigned short* pe_b = (unsigned short*)(wbase + 4 * 524288);
  unsigned short* peT1 = (unsigned short*)(wbase + 4 * 524288 + 77824);
  unsigned short* peB  = (unsigned short*)(wbase + 4 * 524288 + 77824 + 81920);
  unsigned short* peBb = (unsigned short*)(wbase + 4 * 524288 + 77824 + 81920 + 16384);
  char* xbase = wbase + 4 * 524288 + 77824 + 81920 + 16384 + 16384;
  unsigned short* xqb = (unsigned short*)(xbase);
  unsigned short* xkb = (unsigned short*)(xbase + SZ_QKV);
  unsigned short* xvb = (unsigned short*)(xbase + 2 * SZ_QKV);
  const size_t ws_need = (size_t)4 * SZ_QKV + 4 * 524288 + 77824 + 81920 + 16384 + 16384
                       + 3 * SZ_QKV;
  if (ws_size < ws_need) return;

  {
    PrepArgs pa;
    pa.W[0] = Wq; pa.W[1] = Wk; pa.W[2] = Wv; pa.W[3] = Wo;
    pa.Wb[0] = Wqb; pa.Wb[1] = Wkb; pa.Wb[2] = Wvb; pa.Wb[3] = Wob;
    pa.X[0] = query; pa.X[1] = key; pa.X[2] = value;
    pa.Xb[0] = xqb; pa.Xb[1] = xkb; pa.Xb[2] = xvb;
    pa.pe = pe; pa.pe_b = pe_b; pa.peT1 = peT1; pa.peB = peB; pa.peBb = peBb;
    prep_all<<<13472, 256, 0, stream>>>(pa);
  }

  {
    GemmArgs ga;
    ga.A[0] = xqb; ga.A[1] = xkb; ga.A[2] = xvb;
    ga.W[0] = Wqb; ga.W[1] = Wkb; ga.W[2] = Wvb;
    ga.bias[0] = bq; ga.bias[1] = bk; ga.bias[2] = bv;
    ga.scale[0] = ALPHA_Q; ga.scale[1] = 1.f; ga.scale[2] = 1.f;
    ga.Yb[0] = qbuf; ga.Yb[1] = kbuf; ga.Yb[2] = vbuf;
    ga.Yf = nullptr;
    gemm128<0><<<dim3(4, 64, 3), 256, 0, stream>>>(ga);
  }

  attn_mfma<<<1024, 256, 0, stream>>>(qbuf, kbuf, vbuf, pe_b, peT1, peB, peBb, pe, obuf);

  {
    GemmArgs ga;
    ga.A[0] = obuf; ga.A[1] = nullptr; ga.A[2] = nullptr;
    ga.W[0] = Wob;  ga.W[1] = nullptr; ga.W[2] = nullptr;
    ga.bias[0] = bo; ga.bias[1] = nullptr; ga.bias[2] = nullptr;
    ga.scale[0] = 1.f; ga.scale[1] = 1.f; ga.scale[2] = 1.f;
    ga.Yb[0] = nullptr; ga.Yb[1] = nullptr; ga.Yb[2] = nullptr;
    ga.Yf = (float*)d_out;
    gemm128<1><<<dim3(4, 64, 1), 256, 0, stream>>>(ga);
  }
}